// Round 10
// baseline (5677.413 us; speedup 1.0000x reference)
//
#include <hip/hip_runtime.h>
#include <hip/hip_bf16.h>
#include <math.h>

#define BATCH 256
#define SEQN  256
#define INDIM 128
#define HID   512
#define MID   256
#define NCLS  16

#define NG 8     // batch groups
#define RG 32    // rows per group
#define NS 16    // column slices (partner blocks per group)
#define SC 32    // cols per slice (of each of z, r, hh)

typedef _Float16 half8 __attribute__((ext_vector_type(8)));
typedef float    f32x4 __attribute__((ext_vector_type(4)));

// ---- cross-XCD coherent ops (sc1 = device scope; r4/r5/r9-proven) ---------
__device__ __forceinline__ half8 cc_load16(const _Float16* p) {
    half8 r;
    asm volatile("global_load_dwordx4 %0, %1, off sc1" : "=&v"(r) : "v"(p));
    return r;
}
__device__ __forceinline__ void cc_wait() {
    asm volatile("s_waitcnt vmcnt(0)" ::: "memory");
    __builtin_amdgcn_sched_barrier(0);
}
__device__ __forceinline__ void cc_store16(_Float16* p, _Float16 v) {
    unsigned short u = __builtin_bit_cast(unsigned short, v);
    asm volatile("global_store_short %0, %1, off sc1" :: "v"(p), "v"(u) : "memory");
}
__device__ __forceinline__ void cc_store_u32(unsigned int* p, unsigned int v) {
    asm volatile("global_store_dword %0, %1, off sc1" :: "v"(p), "v"(v) : "memory");
}
__device__ __forceinline__ unsigned int cc_load_u32(const unsigned int* p) {
    unsigned int r;
    asm volatile("global_load_dword %0, %1, off sc1\n\ts_waitcnt vmcnt(0)"
                 : "=&v"(r) : "v"(p) : "memory");
    return r;
}

// Per-wave flag wait: flags laid out 4/block (one per wave of the role-set).
// A reader with row-half mt needs waves {mt, mt+2} of all 16 blocks = 32
// slots; 64 lanes poll 2 lanes/slot.
__device__ __forceinline__ void wait_slots(const unsigned int* base, int mt,
                                           int l, unsigned int tgt) {
    const int slot = ((l & 15) << 2) + (((l >> 4) & 1) << 1) + mt;
    for (;;) {
        unsigned int v = cc_load_u32(base + slot);
        if (__all((int)(v >= tgt))) break;
    }
}

// ---------------------------------------------------------------------------
// Weight packs into per-slice B-frag layout (16x16x32 f16 MFMA):
//   B-frag: lane l holds B[k = kt*32 + (l>>4)*8 + j][n = l&15]
// GWA[s][nt4][kt][l][j]  nt4 0,1 = z-ntiles, 2,3 = r-ntiles; K=640 (U | W)
// GWB[s][nt2][kt][l][j]  hh ntiles
// ---------------------------------------------------------------------------
__global__ __launch_bounds__(256) void pack_wA(
    const float* __restrict__ Uz, const float* __restrict__ Ur,
    const float* __restrict__ Wz, const float* __restrict__ Wr,
    _Float16* __restrict__ out)
{
    int idx = blockIdx.x * 256 + threadIdx.x;        // < 16*4*20*512 = 655360
    int j = idx & 7, l = (idx >> 3) & 63;
    int fr = idx >> 9;                               // s*80 + nt4*20 + kt
    int kt = fr % 20; int r2 = fr / 20;
    int nt4 = r2 & 3; int s = r2 >> 2;
    int k = kt * 32 + (l >> 4) * 8 + j;
    int col = s * SC + (nt4 & 1) * 16 + (l & 15);    // 0..511
    const float* U = (nt4 < 2) ? Uz : Ur;
    const float* W = (nt4 < 2) ? Wz : Wr;
    float v = (k < HID) ? U[k * HID + col] : W[(k - HID) * HID + col];
    out[idx] = (_Float16)v;
}

__global__ __launch_bounds__(256) void pack_wB(
    const float* __restrict__ Uh, const float* __restrict__ Wh,
    _Float16* __restrict__ out)
{
    int idx = blockIdx.x * 256 + threadIdx.x;        // < 16*2*20*512 = 327680
    int j = idx & 7, l = (idx >> 3) & 63;
    int fr = idx >> 9;                               // s*40 + nt2*20 + kt
    int kt = fr % 20; int r2 = fr / 20;
    int nt2 = r2 & 1; int s = r2 >> 1;
    int k = kt * 32 + (l >> 4) * 8 + j;
    int col = s * SC + nt2 * 16 + (l & 15);
    float v = (k < HID) ? Uh[k * HID + col] : Wh[(k - HID) * HID + col];
    out[idx] = (_Float16)v;
}

// ---------------------------------------------------------------------------
// Weight-stationary GRU, fully decoupled producer/consumer waves.
// 128 blocks = 8 groups x 16 slices, bid = s*8 + g.
// Waves 4-7: r -> v producers.  Waves 0-3: z + hh consumers (own h update).
// No __syncthreads inside the t-loop; per-wave sc1 flags; HF double-buffered.
// A/H/V-frag: lane l holds A[m=l&15][k = kt*32 + (l>>4)*8 + j]
// C-frag: col = l&15, row = (l>>4)*4 + reg
// ---------------------------------------------------------------------------
__global__ __launch_bounds__(512) void gru_sync(
    const float* __restrict__ x, const _Float16* __restrict__ GWA,
    const _Float16* __restrict__ GWB,
    const float* __restrict__ bz, const float* __restrict__ br,
    const float* __restrict__ bh,
    _Float16* __restrict__ HF, _Float16* __restrict__ VF,
    unsigned int* __restrict__ arr, float* __restrict__ hout)
{
    __shared__ __attribute__((aligned(16))) _Float16 WA[4][20][64][8]; // 80 KB
    __shared__ __attribute__((aligned(16))) _Float16 WB[2][20][64][8]; // 40 KB
    __shared__ float HO[RG][SC];                                        // 4 KB

    const int tid = threadIdx.x;
    const int w = tid >> 6, l = tid & 63;
    const int bid = blockIdx.x;
    const int g = bid & 7, s = bid >> 3;
    const int m = l & 15;
    const int crow0 = (l >> 4) * 4;

    // ---- stage weight slices into LDS ----
    {
        const float4* srcA = (const float4*)&GWA[(size_t)s * (4 * 20 * 512)];
        float4* dstA = (float4*)&WA[0][0][0][0];
        for (int i = tid; i < 4 * 20 * 512 / 8; i += 512) dstA[i] = srcA[i];
        const float4* srcB = (const float4*)&GWB[(size_t)s * (2 * 20 * 512)];
        float4* dstB = (float4*)&WB[0][0][0][0];
        for (int i = tid; i < 2 * 20 * 512 / 8; i += 512) dstB[i] = srcB[i];
    }
    for (int i = tid; i < RG * SC; i += 512) ((float*)HO)[i] = 0.f;

    unsigned int* vfl = &arr[g * 64];          // producer flags, 4/block
    unsigned int* hfl = &arr[512 + g * 64];    // consumer flags, 4/block
    const size_t HFBUF = (size_t)NG * 2 * 16 * 512;   // elements per HF buffer

    __syncthreads();

    if (w >= 4) {
        // ================= PRODUCER: r -> v =================
        const int mt = w & 1;
        const int ct = (w - 4) >> 1;               // r col-tile 0/1
        const float biasA = br[s * SC + ct * 16 + m];
        unsigned int* myflag = &vfl[s * 4 + (w - 4)];

        for (int t = 0; t < SEQN; ++t) {
            // x loads first (independent; in flight during the poll)
            const float* xp = &x[(((size_t)(g * RG + mt * 16 + m)) * SEQN + t) * INDIM + (l >> 4) * 8];
            float4 xa[4], xb[4];
            #pragma unroll
            for (int kf = 0; kf < 4; ++kf) {
                xa[kf] = *(const float4*)(xp + kf * 32);
                xb[kf] = *(const float4*)(xp + kf * 32 + 4);
            }

            wait_slots(hfl, mt, l, (unsigned int)t);   // h(t) ready everywhere

            half8 hfr[16];
            const _Float16* hf = &HF[(t & 1) * HFBUF + (size_t)(g * 2 + mt) * 16 * 512];
            #pragma unroll
            for (int kt = 0; kt < 16; ++kt)
                hfr[kt] = cc_load16(hf + kt * 512 + l * 8);

            half8 xfr[4];
            #pragma unroll
            for (int kf = 0; kf < 4; ++kf) {
                half8 hx;
                hx[0] = (_Float16)xa[kf].x; hx[1] = (_Float16)xa[kf].y;
                hx[2] = (_Float16)xa[kf].z; hx[3] = (_Float16)xa[kf].w;
                hx[4] = (_Float16)xb[kf].x; hx[5] = (_Float16)xb[kf].y;
                hx[6] = (_Float16)xb[kf].z; hx[7] = (_Float16)xb[kf].w;
                xfr[kf] = hx;
            }
            cc_wait();

            f32x4 acc = {0.f, 0.f, 0.f, 0.f};
            #pragma unroll
            for (int kt = 0; kt < 16; ++kt) {
                half8 bf = *(const half8*)&WA[2 + ct][kt][l][0];
                acc = __builtin_amdgcn_mfma_f32_16x16x32_f16(hfr[kt], bf, acc, 0, 0, 0);
            }
            #pragma unroll
            for (int kf = 0; kf < 4; ++kf) {
                half8 bf = *(const half8*)&WA[2 + ct][16 + kf][l][0];
                acc = __builtin_amdgcn_mfma_f32_16x16x32_f16(xfr[kf], bf, acc, 0, 0, 0);
            }
            #pragma unroll
            for (int ri = 0; ri < 4; ++ri) {
                float pre = acc[ri] + biasA;
                float gr = fminf(fmaxf(0.2f * pre + 0.5f, 0.f), 1.f);
                int rloc = mt * 16 + crow0 + ri;
                int cs = ct * 16 + m;
                float vv = gr * HO[rloc][cs];
                cc_store16(&VF[(((size_t)(g * 2 + mt) * 16 + s) * 64 +
                                ((crow0 + ri) + 16 * (cs >> 3))) * 8 + (cs & 7)],
                           (_Float16)vv);
            }
            asm volatile("s_waitcnt vmcnt(0)" ::: "memory");
            if (l == 0) cc_store_u32(myflag, (unsigned int)(t + 1));
        }
    } else {
        // ================= CONSUMER: z + hh + h update =================
        const int mt = w & 1;
        const int ct = w >> 1;                     // z/hh col-tile 0/1
        const float biasA = bz[s * SC + ct * 16 + m];
        const float biasB = bh[s * SC + ct * 16 + m];
        unsigned int* myflag = &hfl[s * 4 + w];

        for (int t = 0; t < SEQN; ++t) {
            const float* xp = &x[(((size_t)(g * RG + mt * 16 + m)) * SEQN + t) * INDIM + (l >> 4) * 8];
            float4 xa[4], xb[4];
            #pragma unroll
            for (int kf = 0; kf < 4; ++kf) {
                xa[kf] = *(const float4*)(xp + kf * 32);
                xb[kf] = *(const float4*)(xp + kf * 32 + 4);
            }

            wait_slots(hfl, mt, l, (unsigned int)t);

            half8 hfr[16];
            const _Float16* hf = &HF[(t & 1) * HFBUF + (size_t)(g * 2 + mt) * 16 * 512];
            #pragma unroll
            for (int kt = 0; kt < 16; ++kt)
                hfr[kt] = cc_load16(hf + kt * 512 + l * 8);

            half8 xfr[4];
            #pragma unroll
            for (int kf = 0; kf < 4; ++kf) {
                half8 hx;
                hx[0] = (_Float16)xa[kf].x; hx[1] = (_Float16)xa[kf].y;
                hx[2] = (_Float16)xa[kf].z; hx[3] = (_Float16)xa[kf].w;
                hx[4] = (_Float16)xb[kf].x; hx[5] = (_Float16)xb[kf].y;
                hx[6] = (_Float16)xb[kf].z; hx[7] = (_Float16)xb[kf].w;
                xfr[kf] = hx;
            }
            cc_wait();

            // ---- z for own tile ----
            f32x4 acc = {0.f, 0.f, 0.f, 0.f};
            #pragma unroll
            for (int kt = 0; kt < 16; ++kt) {
                half8 bf = *(const half8*)&WA[ct][kt][l][0];
                acc = __builtin_amdgcn_mfma_f32_16x16x32_f16(hfr[kt], bf, acc, 0, 0, 0);
            }
            #pragma unroll
            for (int kf = 0; kf < 4; ++kf) {
                half8 bf = *(const half8*)&WA[ct][16 + kf][l][0];
                acc = __builtin_amdgcn_mfma_f32_16x16x32_f16(xfr[kf], bf, acc, 0, 0, 0);
            }
            float zreg[4];
            #pragma unroll
            for (int ri = 0; ri < 4; ++ri) {
                float pre = acc[ri] + biasA;
                zreg[ri] = fminf(fmaxf(0.2f * pre + 0.5f, 0.f), 1.f);
            }

            // ---- wait v, then hh ----
            wait_slots(vfl, mt, l, (unsigned int)(t + 1));

            half8 vfr[16];
            const _Float16* vf = &VF[(size_t)(g * 2 + mt) * 16 * 512];
            #pragma unroll
            for (int kt = 0; kt < 16; ++kt)
                vfr[kt] = cc_load16(vf + kt * 512 + l * 8);
            cc_wait();

            f32x4 acc2 = {0.f, 0.f, 0.f, 0.f};
            #pragma unroll
            for (int kt = 0; kt < 16; ++kt) {
                half8 bf = *(const half8*)&WB[ct][kt][l][0];
                acc2 = __builtin_amdgcn_mfma_f32_16x16x32_f16(vfr[kt], bf, acc2, 0, 0, 0);
            }
            #pragma unroll
            for (int kf = 0; kf < 4; ++kf) {
                half8 bf = *(const half8*)&WB[ct][16 + kf][l][0];
                acc2 = __builtin_amdgcn_mfma_f32_16x16x32_f16(xfr[kf], bf, acc2, 0, 0, 0);
            }

            _Float16* hfo = &HF[((t + 1) & 1) * HFBUF];
            #pragma unroll
            for (int ri = 0; ri < 4; ++ri) {
                float pre = acc2[ri] + biasB;
                float e  = __expf(2.f * pre);
                float hh = 1.f - 2.f / (e + 1.f);          // tanh(pre)
                int rloc = mt * 16 + crow0 + ri;
                int cs = ct * 16 + m;
                float zz = zreg[ri];
                float ho = HO[rloc][cs];
                float hn = zz * ho + (1.f - zz) * hh;
                HO[rloc][cs] = hn;
                cc_store16(&hfo[(((size_t)(g * 2 + mt) * 16 + s) * 64 +
                                 ((crow0 + ri) + 16 * (cs >> 3))) * 8 + (cs & 7)],
                           (_Float16)hn);
            }
            asm volatile("s_waitcnt vmcnt(0) lgkmcnt(0)" ::: "memory");
            if (l == 0) cc_store_u32(myflag, (unsigned int)(t + 1));
        }
    }

    __syncthreads();
    // ---- write final h (own slice, f32) ----
    for (int i = tid; i < RG * SC; i += 512) {
        int r = i >> 5, c = i & 31;
        hout[(size_t)(g * RG + r) * HID + s * SC + c] = HO[r][c];
    }
}

// ---------------------------------------------------------------------------
// Head kernels (unchanged — fp32, proven correct)
// ---------------------------------------------------------------------------
__global__ __launch_bounds__(256) void maxout_k(
    const float* __restrict__ h, const float* __restrict__ moW,
    const float* __restrict__ mob, float* __restrict__ m)
{
    const int ot = blockIdx.x, bt = blockIdx.y;
    __shared__ float sA[32][33];
    __shared__ float sB[4][32][33];
    const int tid = threadIdx.x;
    const int tx = tid & 15, ty = tid >> 4;
    const int b0 = bt * 32, o0 = ot * 32;
    const int lr = tid >> 3, lk4 = (tid & 7) << 2;

    float acc[4][2][2];
    #pragma unroll
    for (int p = 0; p < 4; ++p)
        acc[p][0][0] = acc[p][0][1] = acc[p][1][0] = acc[p][1][1] = 0.f;

    for (int kt = 0; kt < 16; ++kt) {
        const int k0 = kt * 32;
        float4 a = *reinterpret_cast<const float4*>(&h[(b0 + lr) * HID + k0 + lk4]);
        float4 wv[4];
        #pragma unroll
        for (int p = 0; p < 4; ++p)
            wv[p] = *reinterpret_cast<const float4*>(&moW[((size_t)p * HID + k0 + lr) * MID + o0 + lk4]);
        __syncthreads();
        sA[lk4+0][lr] = a.x; sA[lk4+1][lr] = a.y; sA[lk4+2][lr] = a.z; sA[lk4+3][lr] = a.w;
        #pragma unroll
        for (int p = 0; p < 4; ++p) {
            sB[p][lr][lk4+0] = wv[p].x; sB[p][lr][lk4+1] = wv[p].y;
            sB[p][lr][lk4+2] = wv[p].z; sB[p][lr][lk4+3] = wv[p].w;
        }
        __syncthreads();
        #pragma unroll
        for (int kk = 0; kk < 32; ++kk) {
            float a0 = sA[kk][ty*2], a1 = sA[kk][ty*2+1];
            #pragma unroll
            for (int p = 0; p < 4; ++p) {
                float w0 = sB[p][kk][tx*2], w1 = sB[p][kk][tx*2+1];
                acc[p][0][0] += a0*w0; acc[p][0][1] += a0*w1;
                acc[p][1][0] += a1*w0; acc[p][1][1] += a1*w1;
            }
        }
    }

    #pragma unroll
    for (int q = 0; q < 2; ++q)
        #pragma unroll
        for (int c = 0; c < 2; ++c) {
            const int row = b0 + ty*2 + q, col = o0 + tx*2 + c;
            float best = -1e30f;
            #pragma unroll
            for (int p = 0; p < 4; ++p)
                best = fmaxf(best, acc[p][q][c] + mob[p * MID + col]);
            m[row * MID + col] = best;
        }
}

__global__ __launch_bounds__(256) void dense1_k(
    const float* __restrict__ m, const float* __restrict__ W,
    const float* __restrict__ b, float* __restrict__ a1)
{
    const int jt = blockIdx.x, bt = blockIdx.y;
    __shared__ float sA[32][33];
    __shared__ float sB[32][33];
    const int tid = threadIdx.x;
    const int tx = tid & 15, ty = tid >> 4;
    const int b0 = bt * 32, j0 = jt * 32;
    const int lr = tid >> 3, lk4 = (tid & 7) << 2;

    float acc[2][2] = {{0.f,0.f},{0.f,0.f}};

    for (int kt = 0; kt < 8; ++kt) {
        const int k0 = kt * 32;
        float4 a  = *reinterpret_cast<const float4*>(&m[(b0 + lr) * MID + k0 + lk4]);
        float4 bv = *reinterpret_cast<const float4*>(&W[(k0 + lr) * MID + j0 + lk4]);
        __syncthreads();
        sA[lk4+0][lr] = a.x; sA[lk4+1][lr] = a.y; sA[lk4+2][lr] = a.z; sA[lk4+3][lr] = a.w;
        sB[lr][lk4+0] = bv.x; sB[lr][lk4+1] = bv.y; sB[lr][lk4+2] = bv.z; sB[lr][lk4+3] = bv.w;
        __syncthreads();
        #pragma unroll
        for (int kk = 0; kk < 32; ++kk) {
            float a0 = sA[kk][ty*2], a1v = sA[kk][ty*2+1];
            float w0 = sB[kk][tx*2], w1 = sB[kk][tx*2+1];
            acc[0][0] += a0*w0; acc[0][1] += a0*w1;
            acc[1][0] += a1v*w0; acc[1][1] += a1v*w1;
        }
    }

    #pragma unroll
    for (int q = 0; q < 2; ++q)
        #pragma unroll
        for (int c = 0; c < 2; ++c) {
            const int row = b0 + ty*2 + q, col = j0 + tx*2 + c;
            a1[row * MID + col] = acc[q][c] + b[col];
        }
}

__global__ __launch_bounds__(256) void highway_k(
    const float* __restrict__ a1,
    const float* __restrict__ hwW, const float* __restrict__ hwb,
    const float* __restrict__ hwWc, const float* __restrict__ hwbc,
    float* __restrict__ h2)
{
    const int jt = blockIdx.x, bt = blockIdx.y;
    __shared__ float sA[32][33];
    __shared__ float sBh[32][33];
    __shared__ float sBc[32][33];
    const int tid = threadIdx.x;
    const int tx = tid & 15, ty = tid >> 4;
    const int b0 = bt * 32, j0 = jt * 32;
    const int lr = tid >> 3, lk4 = (tid & 7) << 2;

    float acch[2][2] = {{0.f,0.f},{0.f,0.f}};
    float accc[2][2] = {{0.f,0.f},{0.f,0.f}};

    for (int kt = 0; kt < 8; ++kt) {
        const int k0 = kt * 32;
        float4 a   = *reinterpret_cast<const float4*>(&a1[(b0 + lr) * MID + k0 + lk4]);
        float4 bh4 = *reinterpret_cast<const float4*>(&hwW[(k0 + lr) * MID + j0 + lk4]);
        float4 bc4 = *reinterpret_cast<const float4*>(&hwWc[(k0 + lr) * MID + j0 + lk4]);
        __syncthreads();
        sA[lk4+0][lr] = a.x; sA[lk4+1][lr] = a.y; sA[lk4+2][lr] = a.z; sA[lk4+3][lr] = a.w;
        sBh[lr][lk4+0] = bh4.x; sBh[lr][lk4+1] = bh4.y; sBh[lr][lk4+2] = bh4.z; sBh[lr][lk4+3] = bh4.w;
        sBc[lr][lk4+0] = bc4.x; sBc[lr][lk4+1] = bc4.y; sBc[lr][lk4+2] = bc4.z; sBc[lr][lk4+3] = bc4.w;
        __syncthreads();
        #pragma unroll
        for (int kk = 0; kk < 32; ++kk) {
            float a0 = sA[kk][ty*2], a1v = sA[kk][ty*2+1];
            float h0 = sBh[kk][tx*2], h1 = sBh[kk][tx*2+1];
            float c0 = sBc[kk][tx*2], c1 = sBc[kk][tx*2+1];
            acch[0][0] += a0*h0; acch[0][1] += a0*h1;
            acch[1][0] += a1v*h0; acch[1][1] += a1v*h1;
            accc[0][0] += a0*c0; accc[0][1] += a0*c1;
            accc[1][0] += a1v*c0; accc[1][1] += a1v*c1;
        }
    }

    #pragma unroll
    for (int q = 0; q < 2; ++q)
        #pragma unroll
        for (int c = 0; c < 2; ++c) {
            const int row = b0 + ty*2 + q, col = j0 + tx*2 + c;
            float tt = 1.f / (1.f + expf(-(accc[q][c] + hwbc[col])));
            float hp = fmaxf(acch[q][c] + hwb[col], 0.f);
            float av = a1[row * MID + col];
            h2[row * MID + col] = tt * hp + (1.f - tt) * av;
        }
}

__global__ __launch_bounds__(256) void d2_softmax(
    const float* __restrict__ h2, const float* __restrict__ W,
    const float* __restrict__ b, float* __restrict__ out)
{
    const int b0 = blockIdx.x * 16;
    const int r = threadIdx.x >> 4, c = threadIdx.x & 15;
    const int row = b0 + r;

    float acc = b[c];
    for (int i = 0; i < MID; ++i)
        acc += h2[row * MID + i] * W[i * NCLS + c];

    float mx = acc;
    #pragma unroll
    for (int off = 8; off; off >>= 1)
        mx = fmaxf(mx, __shfl_xor(mx, off, 16));
    float e = expf(acc - mx);
    float sm = e;
    #pragma unroll
    for (int off = 8; off; off >>= 1)
        sm += __shfl_xor(sm, off, 16);
    out[row * NCLS + c] = e / sm;
}

// ---------------------------------------------------------------------------
extern "C" void kernel_launch(void* const* d_in, const int* in_sizes, int n_in,
                              void* d_out, int out_size, void* d_ws, size_t ws_size,
                              hipStream_t stream) {
    (void)in_sizes; (void)n_in; (void)out_size; (void)ws_size;

    const float* x    = (const float*)d_in[0];
    const float* Wz   = (const float*)d_in[1];
    const float* Wr   = (const float*)d_in[2];
    const float* Wh   = (const float*)d_in[3];
    const float* Uz   = (const float*)d_in[4];
    const float* Ur   = (const float*)d_in[5];
    const float* Uh   = (const float*)d_in[6];
    const float* bz   = (const float*)d_in[7];
    const float* br   = (const float*)d_in[8];
    const float* bh   = (const float*)d_in[9];
    const float* moW  = (const float*)d_in[10];
    const float* mob  = (const float*)d_in[11];
    const float* d1W  = (const float*)d_in[12];
    const float* d1b  = (const float*)d_in[13];
    const float* hwW  = (const float*)d_in[14];
    const float* hwb  = (const float*)d_in[15];
    const float* hwWc = (const float*)d_in[16];
    const float* hwbc = (const float*)d_in[17];
    const float* d2W  = (const float*)d_in[18];
    const float* d2b  = (const float*)d_in[19];
    float* out = (float*)d_out;

    char* ws = (char*)d_ws;
    _Float16* GWA = (_Float16*)(ws + 0);              // 1,310,720 B
    _Float16* GWB = (_Float16*)(ws + 1310720);        //   655,360 B
    _Float16* HF  = (_Float16*)(ws + 1966080);        //   524,288 B (double buffer)
    _Float16* VF  = (_Float16*)(ws + 2490368);        //   262,144 B
    unsigned int* arr = (unsigned int*)(ws + 2752512);//     4,096 B (per-wave flags)
    float*    hbuf = (float*)(ws + 2756608);          //   524,288 B
    // head temps overlap the GWA region (head runs strictly after gru_sync):
    float*    mxb = (float*)(ws + 0);                 //   262,144 B
    float*    a1b = (float*)(ws + 262144);            //   262,144 B
    float*    h2b = (float*)(ws + 524288);            //   262,144 B

    hipMemsetAsync(HF, 0, 524288, stream);
    hipMemsetAsync(arr, 0, 4096, stream);

    pack_wA<<<2560, 256, 0, stream>>>(Uz, Ur, Wz, Wr, GWA);
    pack_wB<<<1280, 256, 0, stream>>>(Uh, Wh, GWB);

    gru_sync<<<128, 512, 0, stream>>>(x, GWA, GWB, bz, br, bh, HF, VF, arr, hbuf);

    dim3 blk(256);
    maxout_k<<<dim3(8, 8), blk, 0, stream>>>(hbuf, moW, mob, mxb);
    dense1_k<<<dim3(8, 8), blk, 0, stream>>>(mxb, d1W, d1b, a1b);
    highway_k<<<dim3(8, 8), blk, 0, stream>>>(a1b, hwW, hwb, hwWc, hwbc, h2b);
    d2_softmax<<<16, blk, 0, stream>>>(h2b, d2W, d2b, out);
}

// Round 11
// 1741.471 us; speedup vs baseline: 3.2601x; 3.2601x over previous
//
#include <hip/hip_runtime.h>
#include <hip/hip_bf16.h>
#include <math.h>

#define BATCH 256
#define SEQN  256
#define INDIM 128
#define HID   512
#define MID   256
#define NCLS  16

#define NG 8     // batch groups
#define RG 32    // rows per group
#define NS 16    // column slices (partner blocks per group)
#define SC 32    // cols per slice (of each of z, r, hh)

typedef _Float16 half8 __attribute__((ext_vector_type(8)));
typedef float    f32x4 __attribute__((ext_vector_type(4)));

// ---- cross-XCD coherent ops (sc1 = device scope; r4/r5/r9-proven) ---------
__device__ __forceinline__ half8 cc_load16(const _Float16* p) {
    half8 r;
    asm volatile("global_load_dwordx4 %0, %1, off sc1" : "=&v"(r) : "v"(p));
    return r;
}
__device__ __forceinline__ void cc_wait() {
    asm volatile("s_waitcnt vmcnt(0)" ::: "memory");
    __builtin_amdgcn_sched_barrier(0);
}
__device__ __forceinline__ void cc_store16(_Float16* p, _Float16 v) {
    unsigned short u = __builtin_bit_cast(unsigned short, v);
    asm volatile("global_store_short %0, %1, off sc1" :: "v"(p), "v"(u) : "memory");
}
__device__ __forceinline__ void cc_store_u32(unsigned int* p, unsigned int v) {
    asm volatile("global_store_dword %0, %1, off sc1" :: "v"(p), "v"(v) : "memory");
}
__device__ __forceinline__ unsigned int cc_load_u32(const unsigned int* p) {
    unsigned int r;
    asm volatile("global_load_dword %0, %1, off sc1\n\ts_waitcnt vmcnt(0)"
                 : "=&v"(r) : "v"(p) : "memory");
    return r;
}

// Dataflow wait: every wave independently polls the 16 per-block flag slots
// (lane l polls slot l&15; own slot s is exempt — intra-block ordering is
// provided by __syncthreads). Monotonic targets; memset to 0 each launch.
__device__ __forceinline__ void wait_flags(const unsigned int* base, int s,
                                           int l, unsigned int tgt) {
    const int slot = l & 15;
    for (;;) {
        unsigned int v = cc_load_u32(base + slot);
        int ok = (slot == s) || (v >= tgt);
        if (__all(ok)) break;
    }
}

// ---------------------------------------------------------------------------
// Weight packs into per-slice B-frag layout (16x16x32 f16 MFMA):
//   B-frag: lane l holds B[k = kt*32 + (l>>4)*8 + j][n = l&15]
// GWA[s][nt4][kt][l][j]  nt4 0,1 = z-ntiles, 2,3 = r-ntiles; K=640 (U | W)
// GWB[s][nt2][kt][l][j]  hh ntiles
// ---------------------------------------------------------------------------
__global__ __launch_bounds__(256) void pack_wA(
    const float* __restrict__ Uz, const float* __restrict__ Ur,
    const float* __restrict__ Wz, const float* __restrict__ Wr,
    _Float16* __restrict__ out)
{
    int idx = blockIdx.x * 256 + threadIdx.x;        // < 16*4*20*512 = 655360
    int j = idx & 7, l = (idx >> 3) & 63;
    int fr = idx >> 9;                               // s*80 + nt4*20 + kt
    int kt = fr % 20; int r2 = fr / 20;
    int nt4 = r2 & 3; int s = r2 >> 2;
    int k = kt * 32 + (l >> 4) * 8 + j;
    int col = s * SC + (nt4 & 1) * 16 + (l & 15);    // 0..511
    const float* U = (nt4 < 2) ? Uz : Ur;
    const float* W = (nt4 < 2) ? Wz : Wr;
    float v = (k < HID) ? U[k * HID + col] : W[(k - HID) * HID + col];
    out[idx] = (_Float16)v;
}

__global__ __launch_bounds__(256) void pack_wB(
    const float* __restrict__ Uh, const float* __restrict__ Wh,
    _Float16* __restrict__ out)
{
    int idx = blockIdx.x * 256 + threadIdx.x;        // < 16*2*20*512 = 327680
    int j = idx & 7, l = (idx >> 3) & 63;
    int fr = idx >> 9;                               // s*40 + nt2*20 + kt
    int kt = fr % 20; int r2 = fr / 20;
    int nt2 = r2 & 1; int s = r2 >> 1;
    int k = kt * 32 + (l >> 4) * 8 + j;
    int col = s * SC + nt2 * 16 + (l & 15);
    float v = (k < HID) ? Uh[k * HID + col] : Wh[(k - HID) * HID + col];
    out[idx] = (_Float16)v;
}

// ---------------------------------------------------------------------------
// Weight-stationary GRU, dataflow-synchronized. 128 blocks = 8 groups x 16
// slices, bid = s*8 + g. Block (g,s): rows [g*32,+32), cols [s*32,+32) of
// z, r, hh. Weights LDS-resident. Per step: publish flag1 (v ready) and
// flag2 (h ready) after intra-block __syncthreads drains; consumers poll
// per-wave. No group-wide barrier rendezvous on the critical path.
// A/H/V-frag: lane l holds A[m=l&15][k = kt*32 + (l>>4)*8 + j]
// C-frag: col = l&15, row = (l>>4)*4 + reg
// ---------------------------------------------------------------------------
__global__ __launch_bounds__(512) void gru_sync(
    const float* __restrict__ x, const _Float16* __restrict__ GWA,
    const _Float16* __restrict__ GWB,
    const float* __restrict__ bz, const float* __restrict__ br,
    const float* __restrict__ bh,
    _Float16* __restrict__ HF, _Float16* __restrict__ VF,
    unsigned int* __restrict__ arr, float* __restrict__ hout)
{
    __shared__ __attribute__((aligned(16))) _Float16 WA[4][20][64][8]; // 80 KB
    __shared__ __attribute__((aligned(16))) _Float16 WB[2][20][64][8]; // 40 KB
    __shared__ float HO[RG][SC];                                        // 4 KB

    const int tid = threadIdx.x;
    const int w = tid >> 6, l = tid & 63;
    const int bid = blockIdx.x;
    const int g = bid & 7, s = bid >> 3;
    const int m = l & 15;
    const int crow0 = (l >> 4) * 4;

    const int mt  = w & 1;    // m-tile (rows mt*16..+16 of the 32)
    const int nt4 = w >> 1;   // phase A: 0,1 = z-ntiles; 2,3 = r-ntiles
    const int nt2 = w >> 1;   // phase B (w<4 only)

    // ---- stage weight slices into LDS ----
    {
        const float4* srcA = (const float4*)&GWA[(size_t)s * (4 * 20 * 512)];
        float4* dstA = (float4*)&WA[0][0][0][0];
        for (int i = tid; i < 4 * 20 * 512 / 8; i += 512) dstA[i] = srcA[i];
        const float4* srcB = (const float4*)&GWB[(size_t)s * (2 * 20 * 512)];
        float4* dstB = (float4*)&WB[0][0][0][0];
        for (int i = tid; i < 2 * 20 * 512 / 8; i += 512) dstB[i] = srcB[i];
    }
    for (int i = tid; i < RG * SC; i += 512) ((float*)HO)[i] = 0.f;

    // ---- biases (per-wave tile is fixed) ----
    float biasA;
    {
        int col = s * SC + (nt4 & 1) * 16 + m;
        biasA = (nt4 < 2) ? bz[col] : br[col];
    }
    float biasB = 0.f;
    if (w < 4) biasB = bh[s * SC + nt2 * 16 + m];

    unsigned int* f1base = &arr[g * 16];          // v-ready flags  (16 slots)
    unsigned int* f2base = &arr[128 + g * 16];    // h-ready flags  (16 slots)
    unsigned int* f1own  = &arr[g * 16 + s];
    unsigned int* f2own  = &arr[128 + g * 16 + s];
    __syncthreads();

    float zreg[4];    // z values (phase A tile == phase B tile for waves 0..3)
    half8 xfr[4];     // x_t A-frags

    for (int t = 0; t < SEQN; ++t) {
        // ---- x loads first (independent of partners; hide under poll) ----
        float4 xa[4], xb[4];
        {
            const float* xp = &x[(((size_t)(g * RG + mt * 16 + m)) * SEQN + t) * INDIM + (l >> 4) * 8];
            #pragma unroll
            for (int kf = 0; kf < 4; ++kf) {
                xa[kf] = *(const float4*)(xp + kf * 32);
                xb[kf] = *(const float4*)(xp + kf * 32 + 4);
            }
        }

        // ---- dataflow wait: all partners' h for step t published ----
        wait_flags(f2base, s, l, (unsigned int)t);

        // ---- h-exchange loads (16 in flight) ----
        half8 hfr[16];
        {
            const _Float16* hf = &HF[(size_t)(g * 2 + mt) * 16 * 512];
            #pragma unroll
            for (int kt = 0; kt < 16; ++kt)
                hfr[kt] = cc_load16(hf + kt * 512 + l * 8);
        }
        // convert x under the load shadow
        #pragma unroll
        for (int kf = 0; kf < 4; ++kf) {
            half8 hx;
            hx[0] = (_Float16)xa[kf].x; hx[1] = (_Float16)xa[kf].y;
            hx[2] = (_Float16)xa[kf].z; hx[3] = (_Float16)xa[kf].w;
            hx[4] = (_Float16)xb[kf].x; hx[5] = (_Float16)xb[kf].y;
            hx[6] = (_Float16)xb[kf].z; hx[7] = (_Float16)xb[kf].w;
            xfr[kf] = hx;
        }
        cc_wait();

        // ================= phase A: z_s | r_s =================
        {
            f32x4 acc = {0.f, 0.f, 0.f, 0.f};
            #pragma unroll
            for (int kt = 0; kt < 16; ++kt) {
                half8 bf = *(const half8*)&WA[nt4][kt][l][0];
                acc = __builtin_amdgcn_mfma_f32_16x16x32_f16(hfr[kt], bf, acc, 0, 0, 0);
            }
            #pragma unroll
            for (int kf = 0; kf < 4; ++kf) {
                half8 bf = *(const half8*)&WA[nt4][16 + kf][l][0];
                acc = __builtin_amdgcn_mfma_f32_16x16x32_f16(xfr[kf], bf, acc, 0, 0, 0);
            }
            if (nt4 < 2) {
                #pragma unroll
                for (int ri = 0; ri < 4; ++ri) {
                    float pre = acc[ri] + biasA;
                    zreg[ri] = fminf(fmaxf(0.2f * pre + 0.5f, 0.f), 1.f);
                }
            } else {
                #pragma unroll
                for (int ri = 0; ri < 4; ++ri) {
                    float pre = acc[ri] + biasA;
                    float gr = fminf(fmaxf(0.2f * pre + 0.5f, 0.f), 1.f);
                    int rloc = mt * 16 + crow0 + ri;
                    int cs = (nt4 & 1) * 16 + m;
                    float vv = gr * HO[rloc][cs];
                    cc_store16(&VF[(((size_t)(g * 2 + mt) * 16 + s) * 64 +
                                    ((crow0 + ri) + 16 * (cs >> 3))) * 8 + (cs & 7)],
                               (_Float16)vv);
                }
            }
        }

        // ---- publish v: drain all stores block-wide, then set flag1 ----
        asm volatile("s_waitcnt vmcnt(0)" ::: "memory");
        __syncthreads();
        if (tid == 0) cc_store_u32(f1own, (unsigned int)(t + 1));

        // ================= phase B: hh_s, h update =================
        if (w < 4) {
            // dataflow wait: all partners' v for step t published
            wait_flags(f1base, s, l, (unsigned int)(t + 1));

            half8 vfr[16];
            {
                const _Float16* vf = &VF[(size_t)(g * 2 + mt) * 16 * 512];
                #pragma unroll
                for (int kt = 0; kt < 16; ++kt)
                    vfr[kt] = cc_load16(vf + kt * 512 + l * 8);
            }
            cc_wait();

            f32x4 acc2 = {0.f, 0.f, 0.f, 0.f};
            #pragma unroll
            for (int kt = 0; kt < 16; ++kt) {
                half8 bf = *(const half8*)&WB[nt2][kt][l][0];
                acc2 = __builtin_amdgcn_mfma_f32_16x16x32_f16(vfr[kt], bf, acc2, 0, 0, 0);
            }
            #pragma unroll
            for (int kf = 0; kf < 4; ++kf) {
                half8 bf = *(const half8*)&WB[nt2][16 + kf][l][0];
                acc2 = __builtin_amdgcn_mfma_f32_16x16x32_f16(xfr[kf], bf, acc2, 0, 0, 0);
            }
            #pragma unroll
            for (int ri = 0; ri < 4; ++ri) {
                float pre = acc2[ri] + biasB;
                float e  = __expf(2.f * pre);
                float hh = 1.f - 2.f / (e + 1.f);          // tanh(pre)
                int rloc = mt * 16 + crow0 + ri;
                int cs = nt2 * 16 + m;
                float zz = zreg[ri];
                float ho = HO[rloc][cs];
                float hn = zz * ho + (1.f - zz) * hh;
                HO[rloc][cs] = hn;
                cc_store16(&HF[(((size_t)(g * 2 + mt) * 16 + s) * 64 +
                                ((crow0 + ri) + 16 * (cs >> 3))) * 8 + (cs & 7)],
                           (_Float16)hn);
            }
        }

        // ---- publish h': drain, then set flag2 ----
        asm volatile("s_waitcnt vmcnt(0)" ::: "memory");
        __syncthreads();
        if (tid == 0) cc_store_u32(f2own, (unsigned int)(t + 1));
    }

    // ---- write final h (own slice, f32) ----
    for (int i = tid; i < RG * SC; i += 512) {
        int r = i >> 5, c = i & 31;
        hout[(size_t)(g * RG + r) * HID + s * SC + c] = HO[r][c];
    }
}

// ---------------------------------------------------------------------------
// Head kernels (unchanged — fp32, proven correct)
// ---------------------------------------------------------------------------
__global__ __launch_bounds__(256) void maxout_k(
    const float* __restrict__ h, const float* __restrict__ moW,
    const float* __restrict__ mob, float* __restrict__ m)
{
    const int ot = blockIdx.x, bt = blockIdx.y;
    __shared__ float sA[32][33];
    __shared__ float sB[4][32][33];
    const int tid = threadIdx.x;
    const int tx = tid & 15, ty = tid >> 4;
    const int b0 = bt * 32, o0 = ot * 32;
    const int lr = tid >> 3, lk4 = (tid & 7) << 2;

    float acc[4][2][2];
    #pragma unroll
    for (int p = 0; p < 4; ++p)
        acc[p][0][0] = acc[p][0][1] = acc[p][1][0] = acc[p][1][1] = 0.f;

    for (int kt = 0; kt < 16; ++kt) {
        const int k0 = kt * 32;
        float4 a = *reinterpret_cast<const float4*>(&h[(b0 + lr) * HID + k0 + lk4]);
        float4 wv[4];
        #pragma unroll
        for (int p = 0; p < 4; ++p)
            wv[p] = *reinterpret_cast<const float4*>(&moW[((size_t)p * HID + k0 + lr) * MID + o0 + lk4]);
        __syncthreads();
        sA[lk4+0][lr] = a.x; sA[lk4+1][lr] = a.y; sA[lk4+2][lr] = a.z; sA[lk4+3][lr] = a.w;
        #pragma unroll
        for (int p = 0; p < 4; ++p) {
            sB[p][lr][lk4+0] = wv[p].x; sB[p][lr][lk4+1] = wv[p].y;
            sB[p][lr][lk4+2] = wv[p].z; sB[p][lr][lk4+3] = wv[p].w;
        }
        __syncthreads();
        #pragma unroll
        for (int kk = 0; kk < 32; ++kk) {
            float a0 = sA[kk][ty*2], a1 = sA[kk][ty*2+1];
            #pragma unroll
            for (int p = 0; p < 4; ++p) {
                float w0 = sB[p][kk][tx*2], w1 = sB[p][kk][tx*2+1];
                acc[p][0][0] += a0*w0; acc[p][0][1] += a0*w1;
                acc[p][1][0] += a1*w0; acc[p][1][1] += a1*w1;
            }
        }
    }

    #pragma unroll
    for (int q = 0; q < 2; ++q)
        #pragma unroll
        for (int c = 0; c < 2; ++c) {
            const int row = b0 + ty*2 + q, col = o0 + tx*2 + c;
            float best = -1e30f;
            #pragma unroll
            for (int p = 0; p < 4; ++p)
                best = fmaxf(best, acc[p][q][c] + mob[p * MID + col]);
            m[row * MID + col] = best;
        }
}

__global__ __launch_bounds__(256) void dense1_k(
    const float* __restrict__ m, const float* __restrict__ W,
    const float* __restrict__ b, float* __restrict__ a1)
{
    const int jt = blockIdx.x, bt = blockIdx.y;
    __shared__ float sA[32][33];
    __shared__ float sB[32][33];
    const int tid = threadIdx.x;
    const int tx = tid & 15, ty = tid >> 4;
    const int b0 = bt * 32, j0 = jt * 32;
    const int lr = tid >> 3, lk4 = (tid & 7) << 2;

    float acc[2][2] = {{0.f,0.f},{0.f,0.f}};

    for (int kt = 0; kt < 8; ++kt) {
        const int k0 = kt * 32;
        float4 a  = *reinterpret_cast<const float4*>(&m[(b0 + lr) * MID + k0 + lk4]);
        float4 bv = *reinterpret_cast<const float4*>(&W[(k0 + lr) * MID + j0 + lk4]);
        __syncthreads();
        sA[lk4+0][lr] = a.x; sA[lk4+1][lr] = a.y; sA[lk4+2][lr] = a.z; sA[lk4+3][lr] = a.w;
        sB[lr][lk4+0] = bv.x; sB[lr][lk4+1] = bv.y; sB[lr][lk4+2] = bv.z; sB[lr][lk4+3] = bv.w;
        __syncthreads();
        #pragma unroll
        for (int kk = 0; kk < 32; ++kk) {
            float a0 = sA[kk][ty*2], a1v = sA[kk][ty*2+1];
            float w0 = sB[kk][tx*2], w1 = sB[kk][tx*2+1];
            acc[0][0] += a0*w0; acc[0][1] += a0*w1;
            acc[1][0] += a1v*w0; acc[1][1] += a1v*w1;
        }
    }

    #pragma unroll
    for (int q = 0; q < 2; ++q)
        #pragma unroll
        for (int c = 0; c < 2; ++c) {
            const int row = b0 + ty*2 + q, col = j0 + tx*2 + c;
            a1[row * MID + col] = acc[q][c] + b[col];
        }
}

__global__ __launch_bounds__(256) void highway_k(
    const float* __restrict__ a1,
    const float* __restrict__ hwW, const float* __restrict__ hwb,
    const float* __restrict__ hwWc, const float* __restrict__ hwbc,
    float* __restrict__ h2)
{
    const int jt = blockIdx.x, bt = blockIdx.y;
    __shared__ float sA[32][33];
    __shared__ float sBh[32][33];
    __shared__ float sBc[32][33];
    const int tid = threadIdx.x;
    const int tx = tid & 15, ty = tid >> 4;
    const int b0 = bt * 32, j0 = jt * 32;
    const int lr = tid >> 3, lk4 = (tid & 7) << 2;

    float acch[2][2] = {{0.f,0.f},{0.f,0.f}};
    float accc[2][2] = {{0.f,0.f},{0.f,0.f}};

    for (int kt = 0; kt < 8; ++kt) {
        const int k0 = kt * 32;
        float4 a   = *reinterpret_cast<const float4*>(&a1[(b0 + lr) * MID + k0 + lk4]);
        float4 bh4 = *reinterpret_cast<const float4*>(&hwW[(k0 + lr) * MID + j0 + lk4]);
        float4 bc4 = *reinterpret_cast<const float4*>(&hwWc[(k0 + lr) * MID + j0 + lk4]);
        __syncthreads();
        sA[lk4+0][lr] = a.x; sA[lk4+1][lr] = a.y; sA[lk4+2][lr] = a.z; sA[lk4+3][lr] = a.w;
        sBh[lr][lk4+0] = bh4.x; sBh[lr][lk4+1] = bh4.y; sBh[lr][lk4+2] = bh4.z; sBh[lr][lk4+3] = bh4.w;
        sBc[lr][lk4+0] = bc4.x; sBc[lr][lk4+1] = bc4.y; sBc[lr][lk4+2] = bc4.z; sBc[lr][lk4+3] = bc4.w;
        __syncthreads();
        #pragma unroll
        for (int kk = 0; kk < 32; ++kk) {
            float a0 = sA[kk][ty*2], a1v = sA[kk][ty*2+1];
            float h0 = sBh[kk][tx*2], h1 = sBh[kk][tx*2+1];
            float c0 = sBc[kk][tx*2], c1 = sBc[kk][tx*2+1];
            acch[0][0] += a0*h0; acch[0][1] += a0*h1;
            acch[1][0] += a1v*h0; acch[1][1] += a1v*h1;
            accc[0][0] += a0*c0; accc[0][1] += a0*c1;
            accc[1][0] += a1v*c0; accc[1][1] += a1v*c1;
        }
    }

    #pragma unroll
    for (int q = 0; q < 2; ++q)
        #pragma unroll
        for (int c = 0; c < 2; ++c) {
            const int row = b0 + ty*2 + q, col = j0 + tx*2 + c;
            float tt = 1.f / (1.f + expf(-(accc[q][c] + hwbc[col])));
            float hp = fmaxf(acch[q][c] + hwb[col], 0.f);
            float av = a1[row * MID + col];
            h2[row * MID + col] = tt * hp + (1.f - tt) * av;
        }
}

__global__ __launch_bounds__(256) void d2_softmax(
    const float* __restrict__ h2, const float* __restrict__ W,
    const float* __restrict__ b, float* __restrict__ out)
{
    const int b0 = blockIdx.x * 16;
    const int r = threadIdx.x >> 4, c = threadIdx.x & 15;
    const int row = b0 + r;

    float acc = b[c];
    for (int i = 0; i < MID; ++i)
        acc += h2[row * MID + i] * W[i * NCLS + c];

    float mx = acc;
    #pragma unroll
    for (int off = 8; off; off >>= 1)
        mx = fmaxf(mx, __shfl_xor(mx, off, 16));
    float e = expf(acc - mx);
    float sm = e;
    #pragma unroll
    for (int off = 8; off; off >>= 1)
        sm += __shfl_xor(sm, off, 16);
    out[row * NCLS + c] = e / sm;
}

// ---------------------------------------------------------------------------
extern "C" void kernel_launch(void* const* d_in, const int* in_sizes, int n_in,
                              void* d_out, int out_size, void* d_ws, size_t ws_size,
                              hipStream_t stream) {
    (void)in_sizes; (void)n_in; (void)out_size; (void)ws_size;

    const float* x    = (const float*)d_in[0];
    const float* Wz   = (const float*)d_in[1];
    const float* Wr   = (const float*)d_in[2];
    const float* Wh   = (const float*)d_in[3];
    const float* Uz   = (const float*)d_in[4];
    const float* Ur   = (const float*)d_in[5];
    const float* Uh   = (const float*)d_in[6];
    const float* bz   = (const float*)d_in[7];
    const float* br   = (const float*)d_in[8];
    const float* bh   = (const float*)d_in[9];
    const float* moW  = (const float*)d_in[10];
    const float* mob  = (const float*)d_in[11];
    const float* d1W  = (const float*)d_in[12];
    const float* d1b  = (const float*)d_in[13];
    const float* hwW  = (const float*)d_in[14];
    const float* hwb  = (const float*)d_in[15];
    const float* hwWc = (const float*)d_in[16];
    const float* hwbc = (const float*)d_in[17];
    const float* d2W  = (const float*)d_in[18];
    const float* d2b  = (const float*)d_in[19];
    float* out = (float*)d_out;

    char* ws = (char*)d_ws;
    _Float16* GWA = (_Float16*)(ws + 0);              // 1,310,720 B
    _Float16* GWB = (_Float16*)(ws + 1310720);        //   655,360 B
    _Float16* HF  = (_Float16*)(ws + 1966080);        //   262,144 B
    _Float16* VF  = (_Float16*)(ws + 2228224);        //   262,144 B
    unsigned int* arr = (unsigned int*)(ws + 2490368);//     4,096 B (flag slots)
    float*    hbuf = (float*)(ws + 2494464);          //   524,288 B
    // head temps overlap the GWA region (head runs strictly after gru_sync):
    float*    mxb = (float*)(ws + 0);                 //   262,144 B
    float*    a1b = (float*)(ws + 262144);            //   262,144 B
    float*    h2b = (float*)(ws + 524288);            //   262,144 B

    hipMemsetAsync(HF, 0, 262144, stream);
    hipMemsetAsync(arr, 0, 4096, stream);

    pack_wA<<<2560, 256, 0, stream>>>(Uz, Ur, Wz, Wr, GWA);
    pack_wB<<<1280, 256, 0, stream>>>(Uh, Wh, GWB);

    gru_sync<<<128, 512, 0, stream>>>(x, GWA, GWB, bz, br, bh, HF, VF, arr, hbuf);

    dim3 blk(256);
    maxout_k<<<dim3(8, 8), blk, 0, stream>>>(hbuf, moW, mob, mxb);
    dense1_k<<<dim3(8, 8), blk, 0, stream>>>(mxb, d1W, d1b, a1b);
    highway_k<<<dim3(8, 8), blk, 0, stream>>>(a1b, hwW, hwb, hwWc, hwbc, h2b);
    d2_softmax<<<16, blk, 0, stream>>>(h2b, d2W, d2b, out);
}